// Round 11
// baseline (939.850 us; speedup 1.0000x reference)
//
#include <hip/hip_runtime.h>
#include <math.h>
#include <stdint.h>

// ---------------------------------------------------------------------------
// Muskingum-Cunge tree routing, spatially-pipelined persistent kernel, v11.
//
// v10 lesson: batch-granular tag verify makes each stage lag its producer by
// a full batch (B=16 steps) -> pipeline fill ~13*16 = 208 periods ~ 10% of
// runtime. v11 keeps batch-amortized prefetch/publish but makes the DATA
// handoff per-step granular:
//   (1) tag check inline right before step j's use (steady state: first-poll
//       hit, since producers run ahead by slotsB batches).
//   (2) ring store inline right after step j (fire-and-forget).
//   (3) slot back-pressure shifted one batch ahead (end of body(bi) clears
//       slot bi+1 using a counter prefetched at body(bi) start) so inline
//       stores never wait.
//   (4) chain algebra: q' = max(q + dq*rD, 0), dq = 2DT(ti-q) computed
//       straight from q (off-path); D = fmaf(K2, Am, DT) fused. ~8 fewer
//       insts/step, ~2 fewer ops on the critical path.
// Protocol: tagged 8-byte relaxed agent-scope atomics (sc0 sc1, MALL-
// coherent, no bulk cache maintenance), per-wave progress counters, DPP
// pair-sum, no barriers/fences in the steady path.
// ---------------------------------------------------------------------------

#define N_LEVELS   14
#define T_STEPS    2048
#define NR_TOTAL   16383
#define DT_SUB_F   21600.0f
#define EPS_F      1e-6f
#define NBLOCKS    71
#define CTR_STRIDE 8             // ints per wave counter (32 B apart)
#define RING_BYTE_OFF 16384

__device__ __constant__ int kSize[N_LEVELS] = {8192,4096,2048,1024,512,256,128,64,32,16,8,4,2,1};
__device__ __constant__ int kEpb [N_LEVELS] = {256,256,256,256,256,256,128,64,32,16,8,4,2,1};
__device__ __constant__ int kBlkStart[N_LEVELS+1] = {0,32,48,56,60,62,63,64,65,66,67,68,69,70,71};
__device__ __constant__ int kOffL[N_LEVELS] = {0,8192,12288,14336,15360,15872,16128,16256,16320,16352,16368,16376,16380,16382};
// pair-sum entries before level l
__device__ __constant__ int kOffH[N_LEVELS-1] = {0,4096,6144,7168,7680,7936,8064,8128,8160,8176,8184,8188,8190};

#if __has_builtin(__builtin_amdgcn_exp2f)
#define FAST_EXP2(x) __builtin_amdgcn_exp2f(x)
#else
#define FAST_EXP2(x) exp2f(x)
#endif
#if __has_builtin(__builtin_amdgcn_logf)
#define FAST_LOG2(x) __builtin_amdgcn_logf(x)
#else
#define FAST_LOG2(x) log2f(x)
#endif
#if __has_builtin(__builtin_amdgcn_rcpf)
#define FAST_RCP(x) __builtin_amdgcn_rcpf(x)
#else
#define FAST_RCP(x) (1.0f/(x))
#endif

// pair sum of lanes (2k,2k+1) via DPP quad_perm [1,0,3,2]: pure VALU, no LDS.
__device__ __forceinline__ float pair_sum(float x) {
    int yi = __builtin_amdgcn_update_dpp(0, __float_as_int(x),
                                         0xB1 /*quad_perm 1,0,3,2*/,
                                         0xF, 0xF, true);
    return x + __int_as_float(yi);
}

#define ATOMIC_LD_RLX(p)   __hip_atomic_load((p), __ATOMIC_RELAXED, __HIP_MEMORY_SCOPE_AGENT)
#define ATOMIC_ST_RLX(p,v) __hip_atomic_store((p), (v), __ATOMIC_RELAXED, __HIP_MEMORY_SCOPE_AGENT)

template<int B>
__global__ __launch_bounds__(256)
void mc_route_pipe11(const float* __restrict__ lat,
                     const float* __restrict__ logn,
                     const float* __restrict__ len,
                     const float* __restrict__ slope,
                     const float* __restrict__ wcoef,
                     const float* __restrict__ wexp,
                     const float* __restrict__ dcoef,
                     const float* __restrict__ dexp,
                     float* __restrict__ out,
                     int* __restrict__ prog,
                     unsigned long long* __restrict__ ring,
                     int slotsB)
{
    const int bid = blockIdx.x;
    const int tid = threadIdx.x;
    const int NB  = T_STEPS / B;

    int lvl = 0;
#pragma unroll
    for (int l = 1; l < N_LEVELS; ++l)
        if (bid >= kBlkStart[l]) lvl = l;

    const int  bl     = bid - kBlkStart[lvl];
    const int  epb    = kEpb[lvl];
    const int  size   = kSize[lvl];
    const bool validT = (tid < epb);
    const int  e      = bl * epb + (validT ? tid : (epb - 1));
    const int  rr     = kOffL[lvl] + e;

    // -------- per-reach constants (chain-fused form, v5-verified) ----------
    const float dx      = len[rr];
    const float S       = slope[rr];
    const float sqrtS_n = sqrtf(S) * expf(-logn[rr]);        // sqrt(S)/n
    const float de23    = 0.66666667f * dexp[rr];
    const float l2dc    = log2f(dcoef[rr]);
    const float l2base  = log2f(0.6f / sqrtS_n) - 0.66666667f * l2dc;
    const float eK      = -de23;
    const float cK2     = log2f(2.0f * dx) + l2base;
    const float et      = 1.0f - de23 - wexp[rr];
    const float ct      = log2f(0.5f / (S * dx)) + l2base - log2f(wcoef[rr]);

    // -------- pipeline wiring ----------------------------------------------
    const bool hasProd = (lvl > 0);
    const bool hasCons = (lvl < N_LEVELS - 1);
    const int  SBB     = slotsB * B;
    const int  sBm1    = slotsB - 1;
    const unsigned long long* ringUp = hasProd ? ring + (size_t)kOffH[lvl-1] * SBB : ring;
    unsigned long long*       ringMy = hasCons ? ring + (size_t)kOffH[lvl]   * SBB : ring;
    const int halfSize = size >> 1;
    const int upSlotSz = size * B;
    const int mySlotSz = halfSize * B;

    int c0i = 0, c1i = 0;
    if (hasCons) {
        const int ceLo = (bl * epb) >> 1;
        const int ceHi = ((bl + 1) * epb - 1) >> 1;
        const int epbN = kEpb[lvl+1];
        const int cb   = kBlkStart[lvl+1] + ceLo / epbN;
        const int le0  = ceLo - (ceLo / epbN) * epbN;
        const int le1  = ceHi - (ceHi / epbN) * epbN;
        c0i = (cb * 4 + (le0 >> 6)) * CTR_STRIDE;
        c1i = (cb * 4 + (le1 >> 6)) * CTR_STRIDE;
    }
    const int  myCtr    = (bid * 4 + (tid >> 6)) * CTR_STRIDE;
    const bool waveLead = ((tid & 63) == 0);

    float Q = 0.0f, Ip = 0.0f;
    int cachedCons = -0x40000000;

    float latA[B], latB[B];
    unsigned long long pendA[B], pendB[B];

    // -------- prologue: load batch 0 into bank A ---------------------------
#pragma unroll
    for (int j = 0; j < B; ++j)
        latA[j] = lat[(size_t)j * NR_TOTAL + rr];
    if (hasProd && validT) {
#pragma unroll
        for (int j = 0; j < B; ++j)
            pendA[j] = ATOMIC_LD_RLX(ringUp + (size_t)j * size + e);
    }

    auto body = [&](int bi, float* latC, unsigned long long* pendC,
                    float* latN, unsigned long long* pendN) {
        const int tb = bi * B;

        // ---- prefetch NEXT batch into the other bank ----------------------
        if (bi + 1 < NB) {
#pragma unroll
            for (int j = 0; j < B; ++j)
                latN[j] = lat[(size_t)(tb + B + j) * NR_TOTAL + rr];
            if (hasProd && validT) {
                const unsigned long long* upN =
                    ringUp + (size_t)((bi + 1) & sBm1) * upSlotSz + e;
#pragma unroll
                for (int j = 0; j < B; ++j)
                    pendN[j] = ATOMIC_LD_RLX(upN + (size_t)j * size);
            }
        }

        // ---- prefetch consumer progress for NEXT slot (non-blocking) ------
        int pfCons = -0x40000000;
        const int need2 = (bi + 2 - slotsB) * B;         // to free slot bi+1
        if (hasCons && bi + 1 >= slotsB && cachedCons < need2) {
            int v0 = ATOMIC_LD_RLX(&prog[c0i]);
            int v1 = (c1i == c0i) ? v0 : ATOMIC_LD_RLX(&prog[c1i]);
            pfCons = (v0 < v1) ? v0 : v1;
        }

        const unsigned long long* upC = hasProd
            ? ringUp + (size_t)(bi & sBm1) * upSlotSz + e : ring;
        unsigned long long* st = hasCons
            ? ringMy + (size_t)(bi & sBm1) * mySlotSz + (e >> 1) : ringMy;

        // ---- compute the B steps (per-step tag check + store) -------------
#pragma unroll
        for (int j = 0; j < B; ++j) {
            float inflow = latC[j];
            if (hasProd && validT) {
                const unsigned tagWant = (unsigned)(tb + j + 1);
                unsigned long long v = pendC[j];
                int spin = 0;
                while ((unsigned)(v >> 32) != tagWant) {  // steady state: miss ~never
                    if (((++spin) & 63) == 0) __builtin_amdgcn_s_sleep(1);
                    v = ATOMIC_LD_RLX(upC + (size_t)j * size);
                }
                inflow += __uint_as_float((unsigned)v);
            }

            float q = Q;
            const float ti   = inflow;
            const float t13  = ti * (1.0f/3.0f);
            const float t23  = ti * (2.0f/3.0f);
            const float dti  = (2.0f * DT_SUB_F) * ti;
            {   // substep 0: io = Ip
                const float io   = Ip;
                const float sum0 = ti + io;
                float Qref = fmaxf(fmaf(io + q, 1.0f/3.0f, t13), EPS_F);
                float lq   = FAST_LOG2(Qref);
                float K2   = FAST_EXP2(fmaf(eK, lq, cK2));
                float t    = FAST_EXP2(fmaf(et, lq, ct));
                float Xm   = fmaxf(0.5f - t, 0.0f);
                float Am   = fminf(0.5f + t, 1.0f);
                float D    = fmaf(K2, Am, DT_SUB_F);
                float rD   = FAST_RCP(D);
                float br   = fmaf(K2 * Xm, io - ti,
                                  DT_SUB_F * fmaf(-2.0f, q, sum0));
                q = fmaxf(fmaf(br, rD, q), 0.0f);
            }
#pragma unroll
            for (int s = 1; s < 4; ++s) {   // substeps 1..3: io == inflow
                float dq   = fmaf(-2.0f * DT_SUB_F, q, dti);   // 2DT(ti-q), off-path
                float Qref = fmaxf(fmaf(q, 1.0f/3.0f, t23), EPS_F);
                float lq   = FAST_LOG2(Qref);
                float K2   = FAST_EXP2(fmaf(eK, lq, cK2));
                float t    = FAST_EXP2(fmaf(et, lq, ct));
                float Am   = fminf(0.5f + t, 1.0f);
                float D    = fmaf(K2, Am, DT_SUB_F);
                float rD   = FAST_RCP(D);
                q = fmaxf(fmaf(dq, rD, q), 0.0f);
            }
            Q = q; Ip = inflow;

            if (hasCons) {
                float qsum = pair_sum(q);                // DPP, no LDS
                if (validT && ((tid & 1) == 0)) {
                    unsigned long long v =
                        ((unsigned long long)(unsigned)(tb + j + 1) << 32) |
                        (unsigned long long)__float_as_uint(qsum);
                    ATOMIC_ST_RLX(st + (size_t)j * halfSize, v);
                }
            } else if (tid == 0) {
                out[tb + j] = q;
            }
        }

        // ---- publish per-wave consumed progress ---------------------------
        if (waveLead) {
            int pubv = tb + B;
            __asm__ volatile("" : "+v"(pubv) : "v"(Q));  // orders after ring reads
            ATOMIC_ST_RLX(&prog[myCtr], pubv);
        }

        // ---- blocking: ensure slot bi+1 is free before next batch ---------
        if (hasCons && bi + 1 >= slotsB && bi + 1 < NB && cachedCons < need2) {
            if (pfCons >= need2) {
                cachedCons = pfCons;
            } else {
                int spin = 0;
                for (;;) {
                    int v0 = ATOMIC_LD_RLX(&prog[c0i]);
                    int v1 = (c1i == c0i) ? v0 : ATOMIC_LD_RLX(&prog[c1i]);
                    int m  = (v0 < v1) ? v0 : v1;
                    if (m >= need2) { cachedCons = m; break; }
                    if (((++spin) & 63) == 0) __builtin_amdgcn_s_sleep(1);
                }
            }
        }
    };

    // 2x-unrolled batch loop, ping-pong banks (no swap movs)
    for (int bi = 0; bi < NB; bi += 2) {
        body(bi,     latA, pendA, latB, pendB);
        body(bi + 1, latB, pendB, latA, pendA);
    }
}

extern "C" void kernel_launch(void* const* d_in, const int* in_sizes, int n_in,
                              void* d_out, int out_size, void* d_ws, size_t ws_size,
                              hipStream_t stream) {
    const float* lat   = (const float*)d_in[0];
    const float* logn  = (const float*)d_in[1];
    const float* len   = (const float*)d_in[2];
    const float* slope = (const float*)d_in[3];
    const float* wc    = (const float*)d_in[4];
    const float* we    = (const float*)d_in[5];
    const float* dc    = (const float*)d_in[6];
    const float* de    = (const float*)d_in[7];
    float* out = (float*)d_out;

    int* prog = (int*)d_ws;
    unsigned long long* ring = (unsigned long long*)((char*)d_ws + RING_BYTE_OFF);

    auto needBytes = [](int Bv, int Sv) {
        return (size_t)RING_BYTE_OFF + (size_t)8191 * 8 * Bv * Sv;
    };

    if (needBytes(16, 8) <= ws_size) {
        mc_route_pipe11<16><<<NBLOCKS, 256, 0, stream>>>(lat, logn, len, slope, wc, we, dc, de,
                                                         out, prog, ring, 8);
    } else if (needBytes(16, 4) <= ws_size) {
        mc_route_pipe11<16><<<NBLOCKS, 256, 0, stream>>>(lat, logn, len, slope, wc, we, dc, de,
                                                         out, prog, ring, 4);
    } else if (needBytes(16, 2) <= ws_size) {
        mc_route_pipe11<16><<<NBLOCKS, 256, 0, stream>>>(lat, logn, len, slope, wc, we, dc, de,
                                                         out, prog, ring, 2);
    } else if (needBytes(8, 4) <= ws_size) {
        mc_route_pipe11<8><<<NBLOCKS, 256, 0, stream>>>(lat, logn, len, slope, wc, we, dc, de,
                                                        out, prog, ring, 4);
    } else {
        mc_route_pipe11<8><<<NBLOCKS, 256, 0, stream>>>(lat, logn, len, slope, wc, we, dc, de,
                                                        out, prog, ring, 2);
    }
}